// Round 9
// baseline (377.133 us; speedup 1.0000x reference)
//
#include <hip/hip_runtime.h>
#include <stdint.h>

#define N_NODES 50000
#define N_EDGES 800000
#define SPAN_DIM 768
#define EMB_DIM 128
#define HID 256
#define N_TYPES 8
#define NKB (SPAN_DIM / 32)   // 24 k-blocks of 32
#define NNF (HID / 16)        // 16 n-frags of 16
#define NCH 12                // GEMM K-chunks of 64 (2 kb)
#define N_TILES (N_NODES / 16)        // 3125 exact
#define GEMM_GRID 512                 // 2 blocks/CU
#define NRB ((N_NODES + 255) / 256)   // 196 scan blocks

typedef unsigned short u16;
typedef u16 us8 __attribute__((ext_vector_type(8)));
typedef u16 us4 __attribute__((ext_vector_type(4)));
typedef __bf16 bf16x8 __attribute__((ext_vector_type(8)));
typedef float f32x4 __attribute__((ext_vector_type(4)));

// fp32 -> bf16 round-to-nearest-even (bit-exact RNE)
__device__ __forceinline__ u16 f2bf(float f) {
  union { float f; uint32_t u; } v; v.f = f;
  uint32_t u = v.u;
  u += 0x7FFFu + ((u >> 16) & 1u);
  return (u16)(u >> 16);
}
__device__ __forceinline__ float bf2f(u16 x) {
  union { uint32_t u; float f; } v; v.u = ((uint32_t)x) << 16;
  return v.f;
}

// native packed cvt path (v_cvt_pk_bf16_f32, RNE)
__device__ __forceinline__ bf16x8 cvt8(float4 a, float4 b) {
  bf16x8 r;
  r[0] = (__bf16)a.x; r[1] = (__bf16)a.y; r[2] = (__bf16)a.z; r[3] = (__bf16)a.w;
  r[4] = (__bf16)b.x; r[5] = (__bf16)b.y; r[6] = (__bf16)b.z; r[7] = (__bf16)b.w;
  return r;
}

// async global->LDS, 16B per lane; GLOBAL src is PER-LANE, LDS dest is
// wave-uniform base + lane*16.
__device__ __forceinline__ void gload16(const void* g, void* l) {
  __builtin_amdgcn_global_load_lds(
      (__attribute__((address_space(1))) void*)(uintptr_t)g,
      (__attribute__((address_space(3))) void*)l, 16, 0, 0);
}

// ------------- fused prep: W[0:768] bf16 pack (blocks 0..95) + T (96..103) ----
// wp[kb][nf][lane][j] = bf16( W[kb*32 + (lane>>4)*8 + j][nf*16 + (lane&15)] )
__global__ void prep_kernel(const float* __restrict__ emb,
                            const float* __restrict__ W,
                            u16* __restrict__ wp, float* __restrict__ T) {
  if (blockIdx.x < 96) {
    int tid = blockIdx.x * 256 + threadIdx.x;
    int lane = tid & 63;
    int g = tid >> 6;  // kb*16 + nf, 0..383
    int nf = g & 15, kb = g >> 4;
    int k0 = kb * 32 + (lane >> 4) * 8;
    int col = nf * 16 + (lane & 15);
    us8 o;
#pragma unroll
    for (int j = 0; j < 8; ++j) o[j] = f2bf(W[(size_t)(k0 + j) * HID + col]);
    *(us8*)(wp + ((size_t)g * 64 + lane) * 8) = o;
  } else {
    int t = blockIdx.x - 96;  // 0..7
    int c = threadIdx.x;
    float a = 0.f;
    for (int k = 0; k < EMB_DIM; ++k)
      a = fmaf(emb[t * EMB_DIM + k], W[(size_t)(SPAN_DIM + k) * HID + c], a);
    T[(size_t)t * HID + c] = a;
  }
}

// ---------------- degree count over dst ----------------
__global__ void count_kernel(const int* __restrict__ ei, int* __restrict__ cnt) {
  int e = blockIdx.x * 256 + threadIdx.x;
  if (e < N_EDGES) atomicAdd(&cnt[ei[N_EDGES + e]], 1);
}

// ---------------- scan phase 1: per-block sums + dinv ----------------
__global__ void reduce_kernel(const int* __restrict__ cnt, int* __restrict__ bsum,
                              float* __restrict__ dinv) {
  __shared__ int ws[4];
  const int tid = threadIdx.x, lane = tid & 63, wid = tid >> 6;
  const int i = blockIdx.x * 256 + tid;
  int v = (i < N_NODES) ? cnt[i] : 0;
  if (i < N_NODES) dinv[i] = rsqrtf((float)(v + 1));
  int s = v;
#pragma unroll
  for (int d = 32; d; d >>= 1) s += __shfl_down(s, d, 64);
  if (lane == 0) ws[wid] = s;
  __syncthreads();
  if (tid == 0) bsum[blockIdx.x] = ws[0] + ws[1] + ws[2] + ws[3];
}

// ---------------- scan phase 2: 1 wave scans 196 block sums (in place) -------
__global__ void scanb_kernel(int* __restrict__ bsum, int* __restrict__ offsets) {
  const int lane = threadIdx.x;  // 64 threads
  int v[4];
  int s = 0;
#pragma unroll
  for (int k = 0; k < 4; ++k) {
    int idx = lane * 4 + k;
    v[k] = (idx < NRB) ? bsum[idx] : 0;
    s += v[k];
  }
  int incl = s;
#pragma unroll
  for (int d = 1; d < 64; d <<= 1) {
    int t = __shfl_up(incl, d, 64);
    if (lane >= d) incl += t;
  }
  int base = incl - s;  // exclusive base for this lane's range
#pragma unroll
  for (int k = 0; k < 4; ++k) {
    int idx = lane * 4 + k;
    if (idx < NRB) { bsum[idx] = base; base += v[k]; }
  }
  if (lane == 63) offsets[N_NODES] = incl;  // grand total
}

// ---------------- scan phase 3: block-local exclusive scan ----------------
__global__ void scanc_kernel(const int* __restrict__ cnt, const int* __restrict__ bsum,
                             int* __restrict__ offsets, int* __restrict__ cursor) {
  __shared__ int ws[4];
  const int tid = threadIdx.x, lane = tid & 63, wid = tid >> 6;
  const int i = blockIdx.x * 256 + tid;
  int v = (i < N_NODES) ? cnt[i] : 0;
  int s = v;
#pragma unroll
  for (int d = 1; d < 64; d <<= 1) {
    int t = __shfl_up(s, d, 64);
    if (lane >= d) s += t;
  }
  if (lane == 63) ws[wid] = s;
  __syncthreads();
  int wbase = 0;
#pragma unroll
  for (int w = 0; w < 4; ++w) wbase += (w < wid) ? ws[w] : 0;
  if (i < N_NODES) {
    int off = bsum[blockIdx.x] + wbase + s - v;
    offsets[i] = off;
    cursor[i] = off;
  }
}

// ---------------- CSR fill ----------------
__global__ void fill_kernel(const int* __restrict__ ei, int* __restrict__ cursor,
                            int* __restrict__ csr) {
  int e = blockIdx.x * 256 + threadIdx.x;
  if (e < N_EDGES) {
    int d = ei[N_EDGES + e];
    int pos = atomicAdd(&cursor[d], 1);
    csr[pos] = ei[e];
  }
}

// ---------------- h = span @ W_top + T[type]   (bf16 MFMA 16x16x32) ----------
// One wave = ONE 16-row tile x full N=256 (acc[16]); 16 waves/CU.
// Counted-vmcnt schedule (T3/T4), NAMED registers only (rule #20):
//   per chunk: stageB(next) [4 gload_lds] ; sched_barrier(0) ;
//              loadA(next)->named n0..n3 ; MFMA cluster (setprio) ;
//              s_waitcnt vmcnt(4)  (retire own B, A stays in flight) ;
//              s_barrier.
// Chunk loop unrolled x2 so the A register sets alternate as NAMED vars.
__global__ __launch_bounds__(512, 4) void gemm_kernel(
    const float* __restrict__ span, const u16* __restrict__ wp,
    const float* __restrict__ T, const int* __restrict__ type_f,
    u16* __restrict__ h) {
  __shared__ __align__(16) u16 Blds[2][32][64][8];  // 64 KB double buffer
  const int tid = threadIdx.x;
  const int lane = tid & 63;
  const int wv = tid >> 6;
  const int tile = wv * GEMM_GRID + blockIdx.x;  // interleaved: uniform blocks
  const bool active = tile < N_TILES;
  const int tcl = active ? tile : (N_TILES - 1);
  const int p = lane & 15, ko = (lane >> 4) * 8;
  const float* pA = span + (size_t)(tcl * 16 + p) * SPAN_DIM + ko;

  f32x4 acc[16];
#pragma unroll
  for (int nf = 0; nf < 16; ++nf) acc[nf] = (f32x4){0.f, 0.f, 0.f, 0.f};

  auto stageB = [&](int buf, int cc) {
#pragma unroll
    for (int i = 0; i < 4; ++i) {
      const int sl = wv * 4 + i;  // 32 slots of 1KB per chunk
      gload16(wp + (size_t)(cc * 32 + sl) * 512 + (size_t)lane * 8,
              &Blds[buf][sl][0][0]);
    }
  };
  auto compute = [&](int buf, float4 c0, float4 c1, float4 c2, float4 c3) {
    if (!active) return;
    __builtin_amdgcn_s_setprio(1);
    bf16x8 a0 = cvt8(c0, c1);
#pragma unroll
    for (int nf = 0; nf < 16; ++nf) {
      bf16x8 bb = *(const bf16x8*)&Blds[buf][nf][lane][0];
      acc[nf] = __builtin_amdgcn_mfma_f32_16x16x32_bf16(a0, bb, acc[nf], 0, 0, 0);
    }
    bf16x8 a1 = cvt8(c2, c3);
#pragma unroll
    for (int nf = 0; nf < 16; ++nf) {
      bf16x8 bb = *(const bf16x8*)&Blds[buf][16 + nf][lane][0];
      acc[nf] = __builtin_amdgcn_mfma_f32_16x16x32_bf16(a1, bb, acc[nf], 0, 0, 0);
    }
    __builtin_amdgcn_s_setprio(0);
  };

  float4 xa0, xa1, xa2, xa3, ya0, ya1, ya2, ya3;

  // prologue: B(0) then A(0)->x; counted wait retires only B(0)
  stageB(0, 0);
  __builtin_amdgcn_sched_barrier(0);
  {
    const float* q = pA;
    xa0 = *(const float4*)q;       xa1 = *(const float4*)(q + 4);
    xa2 = *(const float4*)(q + 32); xa3 = *(const float4*)(q + 36);
  }
  asm volatile("s_waitcnt vmcnt(4)" ::: "memory");
  __builtin_amdgcn_s_barrier();

#pragma unroll 1
  for (int cc2 = 0; cc2 < NCH; cc2 += 2) {
    // ---- even chunk cc2: compute buf0 from x; prefetch B(cc2+1)->buf1, A->y
    stageB(1, cc2 + 1);
    __builtin_amdgcn_sched_barrier(0);
    {
      const float* q = pA + (cc2 + 1) * 64;
      ya0 = *(const float4*)q;       ya1 = *(const float4*)(q + 4);
      ya2 = *(const float4*)(q + 32); ya3 = *(const float4*)(q + 36);
    }
    compute(0, xa0, xa1, xa2, xa3);
    asm volatile("s_waitcnt vmcnt(4)" ::: "memory");
    __builtin_amdgcn_s_barrier();

    // ---- odd chunk cc2+1: compute buf1 from y; prefetch B(cc2+2)->buf0, A->x
    if (cc2 + 2 < NCH) {
      stageB(0, cc2 + 2);
      __builtin_amdgcn_sched_barrier(0);
      {
        const float* q = pA + (cc2 + 2) * 64;
        xa0 = *(const float4*)q;       xa1 = *(const float4*)(q + 4);
        xa2 = *(const float4*)(q + 32); xa3 = *(const float4*)(q + 36);
      }
      compute(1, ya0, ya1, ya2, ya3);
      asm volatile("s_waitcnt vmcnt(4)" ::: "memory");
      __builtin_amdgcn_s_barrier();
    } else {
      compute(1, ya0, ya1, ya2, ya3);  // last chunk: nothing to prefetch
    }
  }

  if (active) {
    // epilogue: D row=(lane>>4)*4+rg, col=p per frag; pack 4 q-vals per us4.
#pragma unroll
    for (int rg = 0; rg < 4; ++rg) {
      const int r = tile * 16 + ((lane >> 4) << 2) + rg;
      const int ty = type_f[r];
      const float* Tr = T + (size_t)ty * HID;
#pragma unroll
      for (int g = 0; g < 4; ++g) {
        us4 o;
#pragma unroll
        for (int q = 0; q < 4; ++q) {
          const int c = g * 64 + q * 16 + p;
          o[q] = f2bf(acc[g * 4 + q][rg] + Tr[c]);
        }
        *(us4*)(h + (size_t)r * HID + g * 64 + p * 4) = o;
      }
    }
  }
}

// ---------------- aggregate: one wave per node, us4 (8B) per lane ------------
__global__ __launch_bounds__(256) void agg_kernel(
    const u16* __restrict__ h, const int* __restrict__ csr,
    const int* __restrict__ offsets, const float* __restrict__ dinv,
    const float* __restrict__ bias, const float* __restrict__ alpha,
    float* __restrict__ out) {
  const int lane = threadIdx.x & 63;
  const int node = blockIdx.x * 4 + (threadIdx.x >> 6);
  if (node >= N_NODES) return;
  const int blk = lane >> 4, p = lane & 15;
  float bb[4], aa[4];
#pragma unroll
  for (int q = 0; q < 4; ++q) {
    const int c = blk * 64 + q * 16 + p;
    bb[q] = bias[c];
    aa[q] = alpha[c];
  }
  const us4* __restrict__ h4 = (const us4*)h;
  const float di = dinv[node];
  us4 v = h4[(size_t)node * 64 + lane];
  float acc[4];
#pragma unroll
  for (int q = 0; q < 4; ++q) acc[q] = di * bf2f(v[q]);
  const int beg = offsets[node], end = offsets[node + 1];
  int j = beg;
  for (; j + 3 < end; j += 4) {
    const int s0 = csr[j], s1 = csr[j + 1], s2 = csr[j + 2], s3 = csr[j + 3];
    const float w0 = dinv[s0], w1 = dinv[s1], w2 = dinv[s2], w3 = dinv[s3];
    const us4 v0 = h4[(size_t)s0 * 64 + lane];
    const us4 v1 = h4[(size_t)s1 * 64 + lane];
    const us4 v2 = h4[(size_t)s2 * 64 + lane];
    const us4 v3 = h4[(size_t)s3 * 64 + lane];
#pragma unroll
    for (int q = 0; q < 4; ++q) {
      acc[q] = fmaf(w0, bf2f(v0[q]), acc[q]);
      acc[q] = fmaf(w1, bf2f(v1[q]), acc[q]);
      acc[q] = fmaf(w2, bf2f(v2[q]), acc[q]);
      acc[q] = fmaf(w3, bf2f(v3[q]), acc[q]);
    }
  }
  for (; j < end; ++j) {
    const int s0 = csr[j];
    const float w0 = dinv[s0];
    const us4 v0 = h4[(size_t)s0 * 64 + lane];
#pragma unroll
    for (int q = 0; q < 4; ++q) acc[q] = fmaf(w0, bf2f(v0[q]), acc[q]);
  }
#pragma unroll
  for (int q = 0; q < 4; ++q) {
    float r = fmaf(di, acc[q], bb[q]);
    r = r > 0.f ? r : aa[q] * r;
    out[(size_t)node * HID + blk * 64 + q * 16 + p] = r;
  }
}

extern "C" void kernel_launch(void* const* d_in, const int* in_sizes, int n_in,
                              void* d_out, int out_size, void* d_ws, size_t ws_size,
                              hipStream_t stream) {
  const float* span = (const float*)d_in[0];
  const int* type_f = (const int*)d_in[1];
  const int* ei = (const int*)d_in[2];
  const float* emb = (const float*)d_in[3];
  const float* W = (const float*)d_in[4];
  const float* bias = (const float*)d_in[5];
  const float* alpha = (const float*)d_in[6];
  float* out = (float*)d_out;

  char* ws = (char*)d_ws;
  size_t off = 0;
  auto alloc = [&](size_t bytes) {
    char* p = ws + off;
    off = (off + bytes + 255) & ~(size_t)255;
    return p;
  };
  u16* h = (u16*)alloc((size_t)N_NODES * HID * 2);              // 25.6 MB (bf16)
  u16* wp = (u16*)alloc((size_t)NKB * NNF * 64 * 8 * 2);        // 393 KB
  float* T = (float*)alloc((size_t)N_TYPES * HID * 4);          // 8 KB
  int* cnt = (int*)alloc((size_t)N_NODES * 4);
  int* offsets = (int*)alloc((size_t)(N_NODES + 1) * 4);
  int* cursor = (int*)alloc((size_t)N_NODES * 4);
  float* dinv = (float*)alloc((size_t)N_NODES * 4);
  int* bsum = (int*)alloc((size_t)NRB * 4);
  int* csr = (int*)alloc((size_t)N_EDGES * 4);                  // 3.2 MB

  hipMemsetAsync(cnt, 0, (size_t)N_NODES * 4, stream);
  prep_kernel<<<104, 256, 0, stream>>>(emb, W, wp, T);
  count_kernel<<<N_EDGES / 256, 256, 0, stream>>>(ei, cnt);
  reduce_kernel<<<NRB, 256, 0, stream>>>(cnt, bsum, dinv);
  scanb_kernel<<<1, 64, 0, stream>>>(bsum, offsets);
  scanc_kernel<<<NRB, 256, 0, stream>>>(cnt, bsum, offsets, cursor);
  fill_kernel<<<N_EDGES / 256, 256, 0, stream>>>(ei, cursor, csr);
  gemm_kernel<<<GEMM_GRID, 512, 0, stream>>>(span, wp, T, type_f, h);
  agg_kernel<<<(N_NODES + 3) / 4, 256, 0, stream>>>(h, csr, offsets, dinv, bias,
                                                    alpha, out);
}

// Round 10
// 213.374 us; speedup vs baseline: 1.7675x; 1.7675x over previous
//
#include <hip/hip_runtime.h>
#include <stdint.h>

#define N_NODES 50000
#define N_EDGES 800000
#define SPAN_DIM 768
#define EMB_DIM 128
#define HID 256
#define N_TYPES 8
#define NKB (SPAN_DIM / 32)   // 24 k-blocks of 32
#define NNF (HID / 16)        // 16 n-frags of 16
#define NCH 24                // GEMM K-chunks of 32 (BK=32)
#define GEMM_GRID 782         // ceil(50000/64) panels of 64 rows
#define NRB ((N_NODES + 255) / 256)   // 196 scan blocks

typedef unsigned short u16;
typedef u16 us8 __attribute__((ext_vector_type(8)));
typedef u16 us4 __attribute__((ext_vector_type(4)));
typedef __bf16 bf16x8 __attribute__((ext_vector_type(8)));
typedef float f32x4 __attribute__((ext_vector_type(4)));

// fp32 -> bf16 round-to-nearest-even (bit-exact RNE)
__device__ __forceinline__ u16 f2bf(float f) {
  union { float f; uint32_t u; } v; v.f = f;
  uint32_t u = v.u;
  u += 0x7FFFu + ((u >> 16) & 1u);
  return (u16)(u >> 16);
}
__device__ __forceinline__ float bf2f(u16 x) {
  union { uint32_t u; float f; } v; v.u = ((uint32_t)x) << 16;
  return v.f;
}

// native packed cvt path (v_cvt_pk_bf16_f32, RNE)
__device__ __forceinline__ bf16x8 cvt8(float4 a, float4 b) {
  bf16x8 r;
  r[0] = (__bf16)a.x; r[1] = (__bf16)a.y; r[2] = (__bf16)a.z; r[3] = (__bf16)a.w;
  r[4] = (__bf16)b.x; r[5] = (__bf16)b.y; r[6] = (__bf16)b.z; r[7] = (__bf16)b.w;
  return r;
}

// async global->LDS, 16B per lane; GLOBAL src is PER-LANE, LDS dest is
// wave-uniform base + lane*16.
__device__ __forceinline__ void gload16(const void* g, void* l) {
  __builtin_amdgcn_global_load_lds(
      (__attribute__((address_space(1))) void*)(uintptr_t)g,
      (__attribute__((address_space(3))) void*)l, 16, 0, 0);
}

// ------------- fused prep: W[0:768] bf16 pack (blocks 0..95) + T (96..103) ----
// wp[kb][nf][lane][j] = bf16( W[kb*32 + (lane>>4)*8 + j][nf*16 + (lane&15)] )
__global__ void prep_kernel(const float* __restrict__ emb,
                            const float* __restrict__ W,
                            u16* __restrict__ wp, float* __restrict__ T) {
  if (blockIdx.x < 96) {
    int tid = blockIdx.x * 256 + threadIdx.x;
    int lane = tid & 63;
    int g = tid >> 6;  // kb*16 + nf, 0..383
    int nf = g & 15, kb = g >> 4;
    int k0 = kb * 32 + (lane >> 4) * 8;
    int col = nf * 16 + (lane & 15);
    us8 o;
#pragma unroll
    for (int j = 0; j < 8; ++j) o[j] = f2bf(W[(size_t)(k0 + j) * HID + col]);
    *(us8*)(wp + ((size_t)g * 64 + lane) * 8) = o;
  } else {
    int t = blockIdx.x - 96;  // 0..7
    int c = threadIdx.x;
    float a = 0.f;
    for (int k = 0; k < EMB_DIM; ++k)
      a = fmaf(emb[t * EMB_DIM + k], W[(size_t)(SPAN_DIM + k) * HID + c], a);
    T[(size_t)t * HID + c] = a;
  }
}

// ---------------- degree count over dst ----------------
__global__ void count_kernel(const int* __restrict__ ei, int* __restrict__ cnt) {
  int e = blockIdx.x * 256 + threadIdx.x;
  if (e < N_EDGES) atomicAdd(&cnt[ei[N_EDGES + e]], 1);
}

// ---------------- scan phase 1: per-block sums + dinv ----------------
__global__ void reduce_kernel(const int* __restrict__ cnt, int* __restrict__ bsum,
                              float* __restrict__ dinv) {
  __shared__ int ws[4];
  const int tid = threadIdx.x, lane = tid & 63, wid = tid >> 6;
  const int i = blockIdx.x * 256 + tid;
  int v = (i < N_NODES) ? cnt[i] : 0;
  if (i < N_NODES) dinv[i] = rsqrtf((float)(v + 1));
  int s = v;
#pragma unroll
  for (int d = 32; d; d >>= 1) s += __shfl_down(s, d, 64);
  if (lane == 0) ws[wid] = s;
  __syncthreads();
  if (tid == 0) bsum[blockIdx.x] = ws[0] + ws[1] + ws[2] + ws[3];
}

// ---------------- scan phase 2: 1 wave scans 196 block sums (in place) -------
__global__ void scanb_kernel(int* __restrict__ bsum, int* __restrict__ offsets) {
  const int lane = threadIdx.x;  // 64 threads
  int v[4];
  int s = 0;
#pragma unroll
  for (int k = 0; k < 4; ++k) {
    int idx = lane * 4 + k;
    v[k] = (idx < NRB) ? bsum[idx] : 0;
    s += v[k];
  }
  int incl = s;
#pragma unroll
  for (int d = 1; d < 64; d <<= 1) {
    int t = __shfl_up(incl, d, 64);
    if (lane >= d) incl += t;
  }
  int base = incl - s;  // exclusive base for this lane's range
#pragma unroll
  for (int k = 0; k < 4; ++k) {
    int idx = lane * 4 + k;
    if (idx < NRB) { bsum[idx] = base; base += v[k]; }
  }
  if (lane == 63) offsets[N_NODES] = incl;  // grand total
}

// ---------------- scan phase 3: block-local exclusive scan ----------------
__global__ void scanc_kernel(const int* __restrict__ cnt, const int* __restrict__ bsum,
                             int* __restrict__ offsets, int* __restrict__ cursor) {
  __shared__ int ws[4];
  const int tid = threadIdx.x, lane = tid & 63, wid = tid >> 6;
  const int i = blockIdx.x * 256 + tid;
  int v = (i < N_NODES) ? cnt[i] : 0;
  int s = v;
#pragma unroll
  for (int d = 1; d < 64; d <<= 1) {
    int t = __shfl_up(s, d, 64);
    if (lane >= d) s += t;
  }
  if (lane == 63) ws[wid] = s;
  __syncthreads();
  int wbase = 0;
#pragma unroll
  for (int w = 0; w < 4; ++w) wbase += (w < wid) ? ws[w] : 0;
  if (i < N_NODES) {
    int off = bsum[blockIdx.x] + wbase + s - v;
    offsets[i] = off;
    cursor[i] = off;
  }
}

// ---------------- CSR fill ----------------
__global__ void fill_kernel(const int* __restrict__ ei, int* __restrict__ cursor,
                            int* __restrict__ csr) {
  int e = blockIdx.x * 256 + threadIdx.x;
  if (e < N_EDGES) {
    int d = ei[N_EDGES + e];
    int pos = atomicAdd(&cursor[d], 1);
    csr[pos] = ei[e];
  }
}

// ---------------- h = span @ W_top + T[type]   (bf16 MFMA 16x16x32) ----------
// SQUARE wave tiles for fragment reuse: block = 4 waves x (64 rows x 64 cols),
// i.e. 64x256 panel; per kb each wave does 4 A-reads + 4 B-reads -> 16 MFMAs
// (0.5 ds_read/MFMA vs 2.0 in the 16x256 layout). A staged ONCE per block in
// LDS (shared by all 4 waves): global->reg (linear 32B/thread) -> cvt ->
// conflict-free frag-ordered ds_write_b128, issued BEFORE compute (T14).
// B via global_load_lds (L2-hot). Both double-buffered, ONE __syncthreads per
// chunk. LDS 40KB -> 4 independent blocks/CU (16 waves, 4-wave barrier groups).
__global__ __launch_bounds__(256, 4) void gemm_kernel(
    const float* __restrict__ span, const u16* __restrict__ wp,
    const float* __restrict__ T, const int* __restrict__ type_f,
    u16* __restrict__ h) {
  __shared__ __align__(16) u16 Alds[2][4][64][8];   // 8 KB  [buf][rt][kg*16+pr][8]
  __shared__ __align__(16) u16 Blds[2][16][64][8];  // 32 KB [buf][nf][lane][8]
  const int tid = threadIdx.x;
  const int lane = tid & 63;
  const int wc = tid >> 6;          // wave col 0..3 (n-frags wc*4..wc*4+3)
  const int row0 = blockIdx.x * 64;
  const int p = lane & 15;

  // A staging: thread covers row (tid>>2), k-group (tid&3) -> 8 floats (32B)
  const int arow = tid >> 2, akg = tid & 3;
  const int asrc = row0 + arow < N_NODES ? row0 + arow : N_NODES - 1;
  const float* aptr = span + (size_t)asrc * SPAN_DIM + akg * 8;

  f32x4 acc[16];
#pragma unroll
  for (int i = 0; i < 16; ++i) acc[i] = (f32x4){0.f, 0.f, 0.f, 0.f};

  float4 s0, s1;  // A staging regs (consumed same iteration -> single set)
  auto loadA = [&](int cc) {
    const float* q = aptr + cc * 32;
    s0 = *(const float4*)q;
    s1 = *(const float4*)(q + 4);
  };
  auto writeA = [&](int buf) {
    // dest slot akg*16 + (arow&15): 64 lanes -> 64 distinct 16B slots in 1KB
    *(bf16x8*)&Alds[buf][arow >> 4][akg * 16 + (arow & 15)][0] = cvt8(s0, s1);
  };
  auto stageB = [&](int buf, int cc) {
#pragma unroll
    for (int i = 0; i < 4; ++i) {
      const int sl = wc * 4 + i;  // 16 slots of 1KB per chunk
      gload16(wp + (size_t)(cc * 16 + sl) * 512 + (size_t)lane * 8,
              &Blds[buf][sl][0][0]);
    }
  };
  auto compute = [&](int buf) {
    bf16x8 a[4], b[4];
#pragma unroll
    for (int rt = 0; rt < 4; ++rt)
      a[rt] = *(const bf16x8*)&Alds[buf][rt][lane][0];
#pragma unroll
    for (int j = 0; j < 4; ++j)
      b[j] = *(const bf16x8*)&Blds[buf][wc * 4 + j][lane][0];
    __builtin_amdgcn_s_setprio(1);
#pragma unroll
    for (int rt = 0; rt < 4; ++rt)
#pragma unroll
      for (int j = 0; j < 4; ++j)
        acc[rt * 4 + j] =
            __builtin_amdgcn_mfma_f32_16x16x32_bf16(a[rt], b[j], acc[rt * 4 + j], 0, 0, 0);
    __builtin_amdgcn_s_setprio(0);
  };

  // prologue: chunk 0 fully staged
  loadA(0);
  stageB(0, 0);
  writeA(0);
  __syncthreads();

#pragma unroll 1
  for (int cc = 0; cc < NCH; ++cc) {
    const int cur = cc & 1;
    if (cc + 1 < NCH) {
      loadA(cc + 1);            // issue A HBM loads early (hide under compute)
      stageB(cur ^ 1, cc + 1);  // issue B gload_lds early
    }
    compute(cur);
    if (cc + 1 < NCH) writeA(cur ^ 1);  // reg-dep wait + cvt + ds_write late
    __syncthreads();            // drains stage(cc+1); WAR on buf guarded too
  }

  // epilogue: D row=(lane>>4)*4+rg, col=p per frag; pack 4 q-vals per us4.
  // h PERMUTED: slot g*64+p*4+q holds channel g*64+q*16+p; here g == wc.
#pragma unroll
  for (int rt = 0; rt < 4; ++rt) {
#pragma unroll
    for (int rg = 0; rg < 4; ++rg) {
      const int r = row0 + rt * 16 + ((lane >> 4) << 2) + rg;
      if (r < N_NODES) {
        const int ty = type_f[r];
        const float* Tr = T + (size_t)ty * HID;
        us4 o;
#pragma unroll
        for (int q = 0; q < 4; ++q) {
          const int c = wc * 64 + q * 16 + p;
          o[q] = f2bf(acc[rt * 4 + q][rg] + Tr[c]);
        }
        *(us4*)(h + (size_t)r * HID + wc * 64 + p * 4) = o;
      }
    }
  }
}

// ---------------- aggregate: one wave per node, us4 (8B) per lane ------------
__global__ __launch_bounds__(256) void agg_kernel(
    const u16* __restrict__ h, const int* __restrict__ csr,
    const int* __restrict__ offsets, const float* __restrict__ dinv,
    const float* __restrict__ bias, const float* __restrict__ alpha,
    float* __restrict__ out) {
  const int lane = threadIdx.x & 63;
  const int node = blockIdx.x * 4 + (threadIdx.x >> 6);
  if (node >= N_NODES) return;
  const int blk = lane >> 4, p = lane & 15;
  float bb[4], aa[4];
#pragma unroll
  for (int q = 0; q < 4; ++q) {
    const int c = blk * 64 + q * 16 + p;
    bb[q] = bias[c];
    aa[q] = alpha[c];
  }
  const us4* __restrict__ h4 = (const us4*)h;
  const float di = dinv[node];
  us4 v = h4[(size_t)node * 64 + lane];
  float acc[4];
#pragma unroll
  for (int q = 0; q < 4; ++q) acc[q] = di * bf2f(v[q]);
  const int beg = offsets[node], end = offsets[node + 1];
  int j = beg;
  for (; j + 3 < end; j += 4) {
    const int s0 = csr[j], s1 = csr[j + 1], s2 = csr[j + 2], s3 = csr[j + 3];
    const float w0 = dinv[s0], w1 = dinv[s1], w2 = dinv[s2], w3 = dinv[s3];
    const us4 v0 = h4[(size_t)s0 * 64 + lane];
    const us4 v1 = h4[(size_t)s1 * 64 + lane];
    const us4 v2 = h4[(size_t)s2 * 64 + lane];
    const us4 v3 = h4[(size_t)s3 * 64 + lane];
#pragma unroll
    for (int q = 0; q < 4; ++q) {
      acc[q] = fmaf(w0, bf2f(v0[q]), acc[q]);
      acc[q] = fmaf(w1, bf2f(v1[q]), acc[q]);
      acc[q] = fmaf(w2, bf2f(v2[q]), acc[q]);
      acc[q] = fmaf(w3, bf2f(v3[q]), acc[q]);
    }
  }
  for (; j < end; ++j) {
    const int s0 = csr[j];
    const float w0 = dinv[s0];
    const us4 v0 = h4[(size_t)s0 * 64 + lane];
#pragma unroll
    for (int q = 0; q < 4; ++q) acc[q] = fmaf(w0, bf2f(v0[q]), acc[q]);
  }
#pragma unroll
  for (int q = 0; q < 4; ++q) {
    float r = fmaf(di, acc[q], bb[q]);
    r = r > 0.f ? r : aa[q] * r;
    out[(size_t)node * HID + blk * 64 + q * 16 + p] = r;
  }
}

extern "C" void kernel_launch(void* const* d_in, const int* in_sizes, int n_in,
                              void* d_out, int out_size, void* d_ws, size_t ws_size,
                              hipStream_t stream) {
  const float* span = (const float*)d_in[0];
  const int* type_f = (const int*)d_in[1];
  const int* ei = (const int*)d_in[2];
  const float* emb = (const float*)d_in[3];
  const float* W = (const float*)d_in[4];
  const float* bias = (const float*)d_in[5];
  const float* alpha = (const float*)d_in[6];
  float* out = (float*)d_out;

  char* ws = (char*)d_ws;
  size_t off = 0;
  auto alloc = [&](size_t bytes) {
    char* p = ws + off;
    off = (off + bytes + 255) & ~(size_t)255;
    return p;
  };
  u16* h = (u16*)alloc((size_t)N_NODES * HID * 2);              // 25.6 MB (bf16)
  u16* wp = (u16*)alloc((size_t)NKB * NNF * 64 * 8 * 2);        // 393 KB
  float* T = (float*)alloc((size_t)N_TYPES * HID * 4);          // 8 KB
  int* cnt = (int*)alloc((size_t)N_NODES * 4);
  int* offsets = (int*)alloc((size_t)(N_NODES + 1) * 4);
  int* cursor = (int*)alloc((size_t)N_NODES * 4);
  float* dinv = (float*)alloc((size_t)N_NODES * 4);
  int* bsum = (int*)alloc((size_t)NRB * 4);
  int* csr = (int*)alloc((size_t)N_EDGES * 4);                  // 3.2 MB

  hipMemsetAsync(cnt, 0, (size_t)N_NODES * 4, stream);
  prep_kernel<<<104, 256, 0, stream>>>(emb, W, wp, T);
  count_kernel<<<N_EDGES / 256, 256, 0, stream>>>(ei, cnt);
  reduce_kernel<<<NRB, 256, 0, stream>>>(cnt, bsum, dinv);
  scanb_kernel<<<1, 64, 0, stream>>>(bsum, offsets);
  scanc_kernel<<<NRB, 256, 0, stream>>>(cnt, bsum, offsets, cursor);
  fill_kernel<<<N_EDGES / 256, 256, 0, stream>>>(ei, cursor, csr);
  gemm_kernel<<<GEMM_GRID, 256, 0, stream>>>(span, wp, T, type_f, h);
  agg_kernel<<<(N_NODES + 3) / 4, 256, 0, stream>>>(h, csr, offsets, dinv, bias,
                                                    alpha, out);
}

// Round 11
// 188.895 us; speedup vs baseline: 1.9965x; 1.1296x over previous
//
#include <hip/hip_runtime.h>
#include <stdint.h>

#define N_NODES 50000
#define N_EDGES 800000
#define SPAN_DIM 768
#define EMB_DIM 128
#define HID 256
#define N_TYPES 8
#define NKB (SPAN_DIM / 32)   // 24 k-blocks of 32
#define NNF (HID / 16)        // 16 n-frags of 16
#define NCH 12                // GEMM K-chunks of 64 (2 kb)
#define N_TILES (N_NODES / 16)        // 3125 exact
#define GEMM_GRID 512                 // 2 blocks/CU
#define FILL_BLOCKS ((N_EDGES + 511) / 512)  // 1563
#define NRB ((N_NODES + 255) / 256)   // 196 scan blocks

typedef unsigned short u16;
typedef u16 us8 __attribute__((ext_vector_type(8)));
typedef u16 us4 __attribute__((ext_vector_type(4)));
typedef __bf16 bf16x8 __attribute__((ext_vector_type(8)));
typedef float f32x4 __attribute__((ext_vector_type(4)));

// fp32 -> bf16 round-to-nearest-even (bit-exact RNE)
__device__ __forceinline__ u16 f2bf(float f) {
  union { float f; uint32_t u; } v; v.f = f;
  uint32_t u = v.u;
  u += 0x7FFFu + ((u >> 16) & 1u);
  return (u16)(u >> 16);
}
__device__ __forceinline__ float bf2f(u16 x) {
  union { uint32_t u; float f; } v; v.u = ((uint32_t)x) << 16;
  return v.f;
}

// native packed cvt path (v_cvt_pk_bf16_f32, RNE)
__device__ __forceinline__ bf16x8 cvt8(float4 a, float4 b) {
  bf16x8 r;
  r[0] = (__bf16)a.x; r[1] = (__bf16)a.y; r[2] = (__bf16)a.z; r[3] = (__bf16)a.w;
  r[4] = (__bf16)b.x; r[5] = (__bf16)b.y; r[6] = (__bf16)b.z; r[7] = (__bf16)b.w;
  return r;
}

// async global->LDS, 16B per lane; GLOBAL src is PER-LANE, LDS dest is
// wave-uniform base + lane*16.
__device__ __forceinline__ void gload16(const void* g, void* l) {
  __builtin_amdgcn_global_load_lds(
      (__attribute__((address_space(1))) void*)(uintptr_t)g,
      (__attribute__((address_space(3))) void*)l, 16, 0, 0);
}

// ------- fused prep (blocks 0..103: W pack + T) + degree count (104..) -------
// wp[kb][nf][lane][j] = bf16( W[kb*32 + (lane>>4)*8 + j][nf*16 + (lane&15)] )
__global__ void prepcount_kernel(const float* __restrict__ emb,
                                 const float* __restrict__ W,
                                 const int* __restrict__ ei,
                                 u16* __restrict__ wp, float* __restrict__ T,
                                 int* __restrict__ cnt) {
  if (blockIdx.x < 96) {
    int tid = blockIdx.x * 256 + threadIdx.x;
    int lane = tid & 63;
    int g = tid >> 6;  // kb*16 + nf, 0..383
    int nf = g & 15, kb = g >> 4;
    int k0 = kb * 32 + (lane >> 4) * 8;
    int col = nf * 16 + (lane & 15);
    us8 o;
#pragma unroll
    for (int j = 0; j < 8; ++j) o[j] = f2bf(W[(size_t)(k0 + j) * HID + col]);
    *(us8*)(wp + ((size_t)g * 64 + lane) * 8) = o;
  } else if (blockIdx.x < 104) {
    int t = blockIdx.x - 96;  // 0..7
    int c = threadIdx.x;
    float a = 0.f;
    for (int k = 0; k < EMB_DIM; ++k)
      a = fmaf(emb[t * EMB_DIM + k], W[(size_t)(SPAN_DIM + k) * HID + c], a);
    T[(size_t)t * HID + c] = a;
  } else {
    int e = (blockIdx.x - 104) * 256 + threadIdx.x;
    if (e < N_EDGES) atomicAdd(&cnt[ei[N_EDGES + e]], 1);
  }
}

// ---------------- scan phase 1: per-block sums + dinv ----------------
__global__ void reduce_kernel(const int* __restrict__ cnt, int* __restrict__ bsum,
                              float* __restrict__ dinv) {
  __shared__ int ws[4];
  const int tid = threadIdx.x, lane = tid & 63, wid = tid >> 6;
  const int i = blockIdx.x * 256 + tid;
  int v = (i < N_NODES) ? cnt[i] : 0;
  if (i < N_NODES) dinv[i] = rsqrtf((float)(v + 1));
  int s = v;
#pragma unroll
  for (int d = 32; d; d >>= 1) s += __shfl_down(s, d, 64);
  if (lane == 0) ws[wid] = s;
  __syncthreads();
  if (tid == 0) bsum[blockIdx.x] = ws[0] + ws[1] + ws[2] + ws[3];
}

// ---------------- scan phase 2: 1 wave scans 196 block sums (in place) -------
__global__ void scanb_kernel(int* __restrict__ bsum, int* __restrict__ offsets) {
  const int lane = threadIdx.x;  // 64 threads
  int v[4];
  int s = 0;
#pragma unroll
  for (int k = 0; k < 4; ++k) {
    int idx = lane * 4 + k;
    v[k] = (idx < NRB) ? bsum[idx] : 0;
    s += v[k];
  }
  int incl = s;
#pragma unroll
  for (int d = 1; d < 64; d <<= 1) {
    int t = __shfl_up(incl, d, 64);
    if (lane >= d) incl += t;
  }
  int base = incl - s;  // exclusive base for this lane's range
#pragma unroll
  for (int k = 0; k < 4; ++k) {
    int idx = lane * 4 + k;
    if (idx < NRB) { bsum[idx] = base; base += v[k]; }
  }
  if (lane == 63) offsets[N_NODES] = incl;  // grand total
}

// ---------------- scan phase 3: block-local exclusive scan ----------------
__global__ void scanc_kernel(const int* __restrict__ cnt, const int* __restrict__ bsum,
                             int* __restrict__ offsets, int* __restrict__ cursor) {
  __shared__ int ws[4];
  const int tid = threadIdx.x, lane = tid & 63, wid = tid >> 6;
  const int i = blockIdx.x * 256 + tid;
  int v = (i < N_NODES) ? cnt[i] : 0;
  int s = v;
#pragma unroll
  for (int d = 1; d < 64; d <<= 1) {
    int t = __shfl_up(s, d, 64);
    if (lane >= d) s += t;
  }
  if (lane == 63) ws[wid] = s;
  __syncthreads();
  int wbase = 0;
#pragma unroll
  for (int w = 0; w < 4; ++w) wbase += (w < wid) ? ws[w] : 0;
  if (i < N_NODES) {
    int off = bsum[blockIdx.x] + wbase + s - v;
    offsets[i] = off;
    cursor[i] = off;
  }
}

// ---- fused: gemm (blocks 0..511) + CSR fill (blocks 512..2074) --------------
// GEMM: r7 structure (best measured) + double-buffered B -> ONE barrier/chunk.
// One wave = one 16-row tile x full N=256 (acc[16]); 16 waves/CU.
// A: global->reg, one chunk prefetch ahead (named float4 regs). B: 32KB/chunk
// via global_load_lds into alternating buffers (L2-hot).
// Epilogue folds dinv: h_scaled[r] = dinv[r]*(xW + T[ty]), stored bf16
// PERMUTED: slot g*64+p*4+q holds channel g*64+q*16+p (p=lane&15).
__global__ __launch_bounds__(512, 4) void gemmfill_kernel(
    const float* __restrict__ span, const u16* __restrict__ wp,
    const float* __restrict__ T, const int* __restrict__ type_f,
    const float* __restrict__ dinv, const int* __restrict__ ei,
    int* __restrict__ cursor, int* __restrict__ csr, u16* __restrict__ h) {
  __shared__ __align__(16) u16 Blds[2][32][64][8];  // 64 KB double buffer
  if (blockIdx.x >= GEMM_GRID) {  // ---- CSR fill path ----
    int e = (blockIdx.x - GEMM_GRID) * 512 + threadIdx.x;
    if (e < N_EDGES) {
      int d = ei[N_EDGES + e];
      int pos = atomicAdd(&cursor[d], 1);
      csr[pos] = ei[e];
    }
    return;
  }
  const int tid = threadIdx.x;
  const int lane = tid & 63;
  const int wv = tid >> 6;
  const int tile = wv * GEMM_GRID + blockIdx.x;  // interleaved: uniform blocks
  const bool active = tile < N_TILES;
  const int tcl = active ? tile : (N_TILES - 1);
  const int p = lane & 15, ko = (lane >> 4) * 8;
  const float* pA = span + (size_t)(tcl * 16 + p) * SPAN_DIM + ko;

  f32x4 acc[16];
#pragma unroll
  for (int nf = 0; nf < 16; ++nf) acc[nf] = (f32x4){0.f, 0.f, 0.f, 0.f};

  auto stageB = [&](int buf, int cc) {
#pragma unroll
    for (int i = 0; i < 4; ++i) {
      const int sl = wv * 4 + i;  // 32 slots of 1KB per chunk
      gload16(wp + (size_t)(cc * 32 + sl) * 512 + (size_t)lane * 8,
              &Blds[buf][sl][0][0]);
    }
  };

  // prologue: stage B(0) into buf0; preload A chunk 0
  stageB(0, 0);
  float4 c0a = *(const float4*)pA;
  float4 c0b = *(const float4*)(pA + 4);
  float4 c1a = *(const float4*)(pA + 32);
  float4 c1b = *(const float4*)(pA + 36);
  __syncthreads();

#pragma unroll 1
  for (int cc = 0; cc < NCH; ++cc) {
    const int cur = cc & 1;
    if (cc + 1 < NCH) stageB(cur ^ 1, cc + 1);  // B(next) -> other buffer
    // issue next chunk's A loads (named regs; covered by 32 MFMAs + barrier)
    const float* pn = pA + (cc + 1 < NCH ? (cc + 1) * 64 : cc * 64);
    float4 n0a = *(const float4*)pn;
    float4 n0b = *(const float4*)(pn + 4);
    float4 n1a = *(const float4*)(pn + 32);
    float4 n1b = *(const float4*)(pn + 36);

    if (active) {
      __builtin_amdgcn_s_setprio(1);
      bf16x8 a0 = cvt8(c0a, c0b);
#pragma unroll
      for (int nf = 0; nf < 16; ++nf) {
        bf16x8 bb = *(const bf16x8*)&Blds[cur][nf][lane][0];
        acc[nf] = __builtin_amdgcn_mfma_f32_16x16x32_bf16(a0, bb, acc[nf], 0, 0, 0);
      }
      bf16x8 a1 = cvt8(c1a, c1b);
#pragma unroll
      for (int nf = 0; nf < 16; ++nf) {
        bf16x8 bb = *(const bf16x8*)&Blds[cur][16 + nf][lane][0];
        acc[nf] = __builtin_amdgcn_mfma_f32_16x16x32_bf16(a1, bb, acc[nf], 0, 0, 0);
      }
      __builtin_amdgcn_s_setprio(0);
    }
    c0a = n0a; c0b = n0b; c1a = n1a; c1b = n1b;
    __syncthreads();  // B(next) staged; buf(cur) reads done -> safe to reuse
  }

  if (active) {
    // epilogue: D row=(lane>>4)*4+rg, col=p per frag; fold dinv; pack us4.
#pragma unroll
    for (int rg = 0; rg < 4; ++rg) {
      const int r = tile * 16 + ((lane >> 4) << 2) + rg;
      const int ty = type_f[r];
      const float dr = dinv[r];
      const float* Tr = T + (size_t)ty * HID;
#pragma unroll
      for (int g = 0; g < 4; ++g) {
        us4 o;
#pragma unroll
        for (int q = 0; q < 4; ++q) {
          const int c = g * 64 + q * 16 + p;
          o[q] = f2bf(dr * (acc[g * 4 + q][rg] + Tr[c]));
        }
        *(us4*)(h + (size_t)r * HID + g * 64 + p * 4) = o;
      }
    }
  }
}

// ---------------- aggregate: one wave per node, us4 (8B) per lane ------------
// h holds dinv-scaled rows -> inner loop is pure gather+add (no dinv lookup).
__global__ __launch_bounds__(256) void agg_kernel(
    const u16* __restrict__ h, const int* __restrict__ csr,
    const int* __restrict__ offsets, const float* __restrict__ dinv,
    const float* __restrict__ bias, const float* __restrict__ alpha,
    float* __restrict__ out) {
  const int lane = threadIdx.x & 63;
  const int node = blockIdx.x * 4 + (threadIdx.x >> 6);
  if (node >= N_NODES) return;
  const int blk = lane >> 4, p = lane & 15;
  float bb[4], aa[4];
#pragma unroll
  for (int q = 0; q < 4; ++q) {
    const int c = blk * 64 + q * 16 + p;
    bb[q] = bias[c];
    aa[q] = alpha[c];
  }
  const us4* __restrict__ h4 = (const us4*)h;
  const float di = dinv[node];
  us4 v = h4[(size_t)node * 64 + lane];
  float acc[4];
#pragma unroll
  for (int q = 0; q < 4; ++q) acc[q] = bf2f(v[q]);  // self (already scaled)
  const int beg = offsets[node], end = offsets[node + 1];
  int j = beg;
  for (; j + 3 < end; j += 4) {
    const int s0 = csr[j], s1 = csr[j + 1], s2 = csr[j + 2], s3 = csr[j + 3];
    const us4 v0 = h4[(size_t)s0 * 64 + lane];
    const us4 v1 = h4[(size_t)s1 * 64 + lane];
    const us4 v2 = h4[(size_t)s2 * 64 + lane];
    const us4 v3 = h4[(size_t)s3 * 64 + lane];
#pragma unroll
    for (int q = 0; q < 4; ++q)
      acc[q] += bf2f(v0[q]) + bf2f(v1[q]) + bf2f(v2[q]) + bf2f(v3[q]);
  }
  for (; j < end; ++j) {
    const int s0 = csr[j];
    const us4 v0 = h4[(size_t)s0 * 64 + lane];
#pragma unroll
    for (int q = 0; q < 4; ++q) acc[q] += bf2f(v0[q]);
  }
#pragma unroll
  for (int q = 0; q < 4; ++q) {
    float r = fmaf(di, acc[q], bb[q]);
    r = r > 0.f ? r : aa[q] * r;
    out[(size_t)node * HID + blk * 64 + q * 16 + p] = r;
  }
}

extern "C" void kernel_launch(void* const* d_in, const int* in_sizes, int n_in,
                              void* d_out, int out_size, void* d_ws, size_t ws_size,
                              hipStream_t stream) {
  const float* span = (const float*)d_in[0];
  const int* type_f = (const int*)d_in[1];
  const int* ei = (const int*)d_in[2];
  const float* emb = (const float*)d_in[3];
  const float* W = (const float*)d_in[4];
  const float* bias = (const float*)d_in[5];
  const float* alpha = (const float*)d_in[6];
  float* out = (float*)d_out;

  char* ws = (char*)d_ws;
  size_t off = 0;
  auto alloc = [&](size_t bytes) {
    char* p = ws + off;
    off = (off + bytes + 255) & ~(size_t)255;
    return p;
  };
  u16* h = (u16*)alloc((size_t)N_NODES * HID * 2);              // 25.6 MB (bf16)
  u16* wp = (u16*)alloc((size_t)NKB * NNF * 64 * 8 * 2);        // 393 KB
  float* T = (float*)alloc((size_t)N_TYPES * HID * 4);          // 8 KB
  int* cnt = (int*)alloc((size_t)N_NODES * 4);
  int* offsets = (int*)alloc((size_t)(N_NODES + 1) * 4);
  int* cursor = (int*)alloc((size_t)N_NODES * 4);
  float* dinv = (float*)alloc((size_t)N_NODES * 4);
  int* bsum = (int*)alloc((size_t)NRB * 4);
  int* csr = (int*)alloc((size_t)N_EDGES * 4);                  // 3.2 MB

  hipMemsetAsync(cnt, 0, (size_t)N_NODES * 4, stream);
  prepcount_kernel<<<104 + (N_EDGES + 255) / 256, 256, 0, stream>>>(emb, W, ei,
                                                                    wp, T, cnt);
  reduce_kernel<<<NRB, 256, 0, stream>>>(cnt, bsum, dinv);
  scanb_kernel<<<1, 64, 0, stream>>>(bsum, offsets);
  scanc_kernel<<<NRB, 256, 0, stream>>>(cnt, bsum, offsets, cursor);
  gemmfill_kernel<<<GEMM_GRID + FILL_BLOCKS, 512, 0, stream>>>(
      span, wp, T, type_f, dinv, ei, cursor, csr, h);
  agg_kernel<<<(N_NODES + 3) / 4, 256, 0, stream>>>(h, csr, offsets, dinv, bias,
                                                    alpha, out);
}